// Round 9
// baseline (179.181 us; speedup 1.0000x reference)
//
#include <hip/hip_runtime.h>

typedef unsigned short USH;
typedef unsigned int   UIN;

static constexpr int Bn = 1024;    // batch
static constexpr int Hn = 200;     // history length
static constexpr int Dn = 128;     // embed/hidden
static constexpr int Dh = 64;      // half embed
static constexpr int NITEM = 50000;
static constexpr int NREG  = 1000;
static constexpr int MT = 64;      // items per ab block
static constexpr int AB_A_BLOCKS = (NITEM + MT - 1) / MT;  // 782
static constexpr int AB_B_BLOCKS = (NREG  + MT - 1) / MT;  // 16
static constexpr int WTS = 132;    // wt stride (floats)
static constexpr int ETS = 69;     // et stride (floats)
static constexpr int KROWS = 100;  // kv rows per chunk (a<64 -> t<=99)

__device__ __forceinline__ float bf2f(USH u) {
  return __uint_as_float(((UIN)u) << 16);
}
__device__ __forceinline__ float2 pb2f2(UIN p) {  // packed bf16 pair -> 2 floats
  float2 r;
  r.x = __uint_as_float(p << 16);
  r.y = __uint_as_float(p & 0xffff0000u);
  return r;
}
__device__ __forceinline__ USH f2b(float f) {  // fp32 -> bf16 rne
  UIN x = __float_as_uint(f);
  return (USH)((x + 0x7fffu + ((x >> 16) & 1u)) >> 16);
}
__device__ __forceinline__ UIN addpk(UIN u, UIN v) {  // bf16x2 + bf16x2
  float2 a = pb2f2(u), b = pb2f2(v);
  return (UIN)f2b(a.x + b.x) | ((UIN)f2b(a.y + b.y) << 16);
}

// ---------------------------------------------------------------------------
// g[c] = sum_i row[tr[i]] * row[hr[i,c]],  row = embed_dist[uid]  (fp32)
// ---------------------------------------------------------------------------
__global__ __launch_bounds__(256) void g_kernel(
    const int* __restrict__ hregion, const int* __restrict__ tregion,
    const float* __restrict__ embed_dist, const int* __restrict__ uid,
    float* __restrict__ g) {
  int c = threadIdx.x;
  const float* row = embed_dist + (size_t)uid[0] * NREG;  // 4KB, L1-resident
  float acc = 0.f;
  int ibase = blockIdx.x * 16;
  for (int ii = 0; ii < 16; ii++) {
    int i = ibase + ii;
    float td = row[tregion[i]];               // wave-uniform broadcast
    if (c < Hn) acc += td * row[hregion[(size_t)i * Hn + c]];
  }
  if (c < Hn) atomicAdd(&g[c], acc);
}

// ---------------------------------------------------------------------------
// A[item][j] = dot(Et[item][0:64], Wk[j][0:64])   -> bf16 table
// B[reg][j]  = dot(Er[reg][0:64],  Wk[j][64:128]) -> bf16 table
// Register-tiled GEMM (accumulator tile 4x8 cannot be rematerialized).
// Also emits bf16 copies of the raw E rows for main's s1/s2 gathers.
// ---------------------------------------------------------------------------
__global__ __launch_bounds__(256, 2) void ab_kernel(
    const float* __restrict__ Et, const float* __restrict__ Er,
    const float* __restrict__ Wk, USH* __restrict__ A, USH* __restrict__ Bt,
    USH* __restrict__ Ebr, USH* __restrict__ Err, int emit_raw) {
  __shared__ float wt[64 * WTS];  // 33.8KB: wt[k*WTS + j] = Wk[j][koff+k]
  __shared__ float et[MT * ETS];  // 17.7KB: et[m*ETS + k] = E[base+m][k]
  int blk = blockIdx.x, tid = threadIdx.x;
  const float* E; USH* Out; USH* OutR; int nmax, base, koff;
  if (blk < AB_A_BLOCKS) { E = Et; Out = A;  OutR = Ebr; nmax = NITEM; base = blk * MT; koff = 0; }
  else { E = Er; Out = Bt; OutR = Err; nmax = NREG; base = (blk - AB_A_BLOCKS) * MT; koff = 64; }

  // stage Wk transposed
#pragma unroll
  for (int p = 0; p < 8; p++) {
    int idx = p * 256 + tid;
    int row = idx >> 4, c4 = idx & 15;
    float4 w = *reinterpret_cast<const float4*>(Wk + (size_t)row * Dn + koff + c4 * 4);
    wt[(c4 * 4 + 0) * WTS + row] = w.x;
    wt[(c4 * 4 + 1) * WTS + row] = w.y;
    wt[(c4 * 4 + 2) * WTS + row] = w.z;
    wt[(c4 * 4 + 3) * WTS + row] = w.w;
  }
  // stage E rows row-major
#pragma unroll
  for (int p = 0; p < 4; p++) {
    int idx = p * 256 + tid;
    int m = idx >> 4, c4 = idx & 15;
    int gi = base + m;
    float4 e = make_float4(0.f, 0.f, 0.f, 0.f);
    if (gi < nmax) e = *reinterpret_cast<const float4*>(E + (size_t)gi * Dh + c4 * 4);
    et[m * ETS + c4 * 4 + 0] = e.x;
    et[m * ETS + c4 * 4 + 1] = e.y;
    et[m * ETS + c4 * 4 + 2] = e.z;
    et[m * ETS + c4 * 4 + 3] = e.w;
  }
  __syncthreads();

  // bf16 copy of raw E rows (for main's s1/s2)
  if (emit_raw) {
#pragma unroll
    for (int q = 0; q < 8; q++) {
      int idx = q * 256 + tid;       // 0..2047
      int m = idx >> 5, kp = idx & 31;
      int gi = base + m;
      if (gi < nmax) {
        UIN pk = (UIN)f2b(et[m * ETS + 2 * kp]) | ((UIN)f2b(et[m * ETS + 2 * kp + 1]) << 16);
        *reinterpret_cast<UIN*>(OutR + (size_t)gi * Dh + 2 * kp) = pk;
      }
    }
  }

  int jt = tid & 15, it = tid >> 4;     // 8 j's, 4 items per thread
  const float* wb = wt + jt * 8;
  const float* eb = et + (it * 4) * ETS;
  float c[4][8];
#pragma unroll
  for (int ii = 0; ii < 4; ii++)
#pragma unroll
    for (int jj = 0; jj < 8; jj++) c[ii][jj] = 0.f;

#pragma unroll 2
  for (int k = 0; k < 64; k++) {
    float4 w0 = *reinterpret_cast<const float4*>(wb + (size_t)k * WTS);
    float4 w1 = *reinterpret_cast<const float4*>(wb + (size_t)k * WTS + 4);
    float e0 = eb[k], e1 = eb[ETS + k], e2 = eb[2 * ETS + k], e3 = eb[3 * ETS + k];
    c[0][0] += e0 * w0.x; c[0][1] += e0 * w0.y; c[0][2] += e0 * w0.z; c[0][3] += e0 * w0.w;
    c[0][4] += e0 * w1.x; c[0][5] += e0 * w1.y; c[0][6] += e0 * w1.z; c[0][7] += e0 * w1.w;
    c[1][0] += e1 * w0.x; c[1][1] += e1 * w0.y; c[1][2] += e1 * w0.z; c[1][3] += e1 * w0.w;
    c[1][4] += e1 * w1.x; c[1][5] += e1 * w1.y; c[1][6] += e1 * w1.z; c[1][7] += e1 * w1.w;
    c[2][0] += e2 * w0.x; c[2][1] += e2 * w0.y; c[2][2] += e2 * w0.z; c[2][3] += e2 * w0.w;
    c[2][4] += e2 * w1.x; c[2][5] += e2 * w1.y; c[2][6] += e2 * w1.z; c[2][7] += e2 * w1.w;
    c[3][0] += e3 * w0.x; c[3][1] += e3 * w0.y; c[3][2] += e3 * w0.z; c[3][3] += e3 * w0.w;
    c[3][4] += e3 * w1.x; c[3][5] += e3 * w1.y; c[3][6] += e3 * w1.z; c[3][7] += e3 * w1.w;
  }

#pragma unroll
  for (int ii = 0; ii < 4; ii++) {
    int item = base + it * 4 + ii;
    if (item < nmax) {
      uint4 pk;
      pk.x = (UIN)f2b(c[ii][0]) | ((UIN)f2b(c[ii][1]) << 16);
      pk.y = (UIN)f2b(c[ii][2]) | ((UIN)f2b(c[ii][3]) << 16);
      pk.z = (UIN)f2b(c[ii][4]) | ((UIN)f2b(c[ii][5]) << 16);
      pk.w = (UIN)f2b(c[ii][6]) | ((UIN)f2b(c[ii][7]) << 16);
      *reinterpret_cast<uint4*>(Out + (size_t)item * Dn + jt * 8) = pk;
    }
  }
}

// ---------------------------------------------------------------------------
// One block per batch row i. a-chunked scores (100-row kv buffer staged
// twice, 27.2KB LDS -> 5 blocks/CU by LDS). v9: launch_bounds(256,4) —
// r8's (256,5) squeezed VGPRs to 48 and spilled 6.6MB to scratch per
// dispatch; (256,4) allows the ~80 VGPRs the code needs, LDS still caps
// occupancy at 5 blocks/CU. Spill-free + high occupancy.
// ---------------------------------------------------------------------------
__global__ __launch_bounds__(256, 4) void main_kernel(
    const int* __restrict__ history, const int* __restrict__ target,
    const int* __restrict__ hregion, const int* __restrict__ tregion,
    const float* __restrict__ hv, const float* __restrict__ dist_mat,
    const float* __restrict__ Et, const float* __restrict__ Er,
    const float* __restrict__ Wq, const float* __restrict__ Wv,
    const float* __restrict__ g, const USH* __restrict__ A,
    const USH* __restrict__ Bt, const USH* __restrict__ Ebr,
    const USH* __restrict__ Err, int use_raw, float* __restrict__ out) {
  __shared__ USH kvs[KROWS * Dn];   // 25600B, reused for both chunks
  __shared__ float tgtE[128], qv[128], uv[128];
  __shared__ float red[8];          // total 27168B -> 5 blocks/CU
  int i = blockIdx.x, tid = threadIdx.x, lane = tid & 63, wave = tid >> 6;
  int tgt_i = target[i], tr_i = tregion[i];
  const int* hrow = history + (size_t)i * Hn;
  const int* rrow = hregion + (size_t)i * Hn;

  if (tid < 64)       tgtE[tid] = Et[(size_t)tgt_i * Dh + tid];
  else if (tid < 128) tgtE[tid] = Er[(size_t)tr_i * Dh + (tid - 64)];

  int rlane = tid & 15, rgrp = tid >> 4;   // 16 rows per staging pass
  // ---- stage chunk 1: kv rows t = 0..99 ----
#pragma unroll
  for (int p = 0; p < 7; p++) {
    int t = p * 16 + rgrp;
    if (t < KROWS) {
      int ia = hrow[t], ib = rrow[t];
      uint4 av = *reinterpret_cast<const uint4*>(A  + (size_t)ia * Dn + rlane * 8);
      uint4 bv = *reinterpret_cast<const uint4*>(Bt + (size_t)ib * Dn + rlane * 8);
      uint4 pk;
      pk.x = addpk(av.x, bv.x); pk.y = addpk(av.y, bv.y);
      pk.z = addpk(av.z, bv.z); pk.w = addpk(av.w, bv.w);
      *reinterpret_cast<uint4*>(&kvs[t * Dn + rlane * 8]) = pk;
    }
  }
  __syncthreads();

  // ---- qv (waves 0-1) / uv (waves 2-3) ----
  if (tid < 128) {
    int j = tid; float acc = 0.f;
    const float4* wp = reinterpret_cast<const float4*>(Wq + (size_t)j * Dn);
#pragma unroll
    for (int q4 = 0; q4 < 32; q4++) {
      float4 w = wp[q4];
      const float* tv = &tgtE[q4 * 4];
      acc += w.x * tv[0] + w.y * tv[1] + w.z * tv[2] + w.w * tv[3];
    }
    qv[j] = acc * 0.088388347648318447f;  // 1/sqrt(128) folded into q
  } else {
    int d = tid - 128;
    float a0 = 0.f, a1 = 0.f, a2 = 0.f, a3 = 0.f;
#pragma unroll 8
    for (int j = 0; j < 128; j += 4) {
      a0 += Wv[(size_t)(j + 0) * Dn + d] * tgtE[j + 0];
      a1 += Wv[(size_t)(j + 1) * Dn + d] * tgtE[j + 1];
      a2 += Wv[(size_t)(j + 2) * Dn + d] * tgtE[j + 2];
      a3 += Wv[(size_t)(j + 3) * Dn + d] * tgtE[j + 3];
    }
    uv[d] = (a0 + a1) + (a2 + a3);
  }
  __syncthreads();

  float ea = 0.f, sc1 = 0.f, sc2 = 0.f, acc = 0.f;
  if (tid < Hn) {
    // s1/s2 first: global bf16-row loads overlap the LDS score loop
    int ia2 = hrow[tid], ib2 = rrow[tid];
    float p1 = 0.f, p2 = 0.f;
    if (use_raw) {
      const uint4* epu = reinterpret_cast<const uint4*>(Ebr + (size_t)ia2 * Dh);
      const uint4* rpu = reinterpret_cast<const uint4*>(Err + (size_t)ib2 * Dh);
#pragma unroll
      for (int k8 = 0; k8 < 8; k8++) {
        uint4 e = epu[k8], r = rpu[k8];
        float2 e0 = pb2f2(e.x), e1 = pb2f2(e.y), e2 = pb2f2(e.z), e3 = pb2f2(e.w);
        float2 r0 = pb2f2(r.x), r1 = pb2f2(r.y), r2 = pb2f2(r.z), r3 = pb2f2(r.w);
        const float* u0 = &uv[k8 * 8];       const float* t0 = &tgtE[k8 * 8];
        const float* u1 = &uv[64 + k8 * 8];  const float* t1 = &tgtE[64 + k8 * 8];
        p1 += e0.x * u0[0] + e0.y * u0[1] + e1.x * u0[2] + e1.y * u0[3]
            + e2.x * u0[4] + e2.y * u0[5] + e3.x * u0[6] + e3.y * u0[7]
            + r0.x * u1[0] + r0.y * u1[1] + r1.x * u1[2] + r1.y * u1[3]
            + r2.x * u1[4] + r2.y * u1[5] + r3.x * u1[6] + r3.y * u1[7];
        p2 += e0.x * t0[0] + e0.y * t0[1] + e1.x * t0[2] + e1.y * t0[3]
            + e2.x * t0[4] + e2.y * t0[5] + e3.x * t0[6] + e3.y * t0[7]
            + r0.x * t1[0] + r0.y * t1[1] + r1.x * t1[2] + r1.y * t1[3]
            + r2.x * t1[4] + r2.y * t1[5] + r3.x * t1[6] + r3.y * t1[7];
      }
    } else {
      const float4* ep = reinterpret_cast<const float4*>(Et + (size_t)ia2 * Dh);
      const float4* rp = reinterpret_cast<const float4*>(Er + (size_t)ib2 * Dh);
#pragma unroll
      for (int k4 = 0; k4 < 16; k4++) {
        float4 e = ep[k4], r = rp[k4];
        const float* u0 = &uv[k4 * 4];        const float* t0 = &tgtE[k4 * 4];
        const float* u1 = &uv[64 + k4 * 4];   const float* t1 = &tgtE[64 + k4 * 4];
        p1 += e.x * u0[0] + e.y * u0[1] + e.z * u0[2] + e.w * u0[3]
            + r.x * u1[0] + r.y * u1[1] + r.z * u1[2] + r.w * u1[3];
        p2 += e.x * t0[0] + e.y * t0[1] + e.z * t0[2] + e.w * t0[3]
            + r.x * t1[0] + r.y * t1[1] + r.z * t1[2] + r.w * t1[3];
      }
    }
    sc1 = p1; sc2 = p2;
    // scores chunk 1: a = 0..63 (kvs halfword index a*200+c, max 12799)
    const USH* kp = &kvs[tid];
#pragma unroll 16
    for (int a = 0; a < 64; a++) acc += qv[a] * bf2f(kp[a * 200]);
  }
  __syncthreads();  // chunk-1 buffer fully consumed

  // ---- stage chunk 2: kv rows t = 100..199 into the same buffer ----
#pragma unroll
  for (int p = 0; p < 7; p++) {
    int t = KROWS + p * 16 + rgrp;
    if (t < Hn) {
      int ia = hrow[t], ib = rrow[t];
      uint4 av = *reinterpret_cast<const uint4*>(A  + (size_t)ia * Dn + rlane * 8);
      uint4 bv = *reinterpret_cast<const uint4*>(Bt + (size_t)ib * Dn + rlane * 8);
      uint4 pk;
      pk.x = addpk(av.x, bv.x); pk.y = addpk(av.y, bv.y);
      pk.z = addpk(av.z, bv.z); pk.w = addpk(av.w, bv.w);
      *reinterpret_cast<uint4*>(&kvs[(t - KROWS) * Dn + rlane * 8]) = pk;
    }
  }
  __syncthreads();

  if (tid < Hn) {
    // scores chunk 2: buffer index (a-64)*200+c — same pattern
    const USH* kp = &kvs[tid];
#pragma unroll 16
    for (int a = 0; a < 64; a++) acc += qv[64 + a] * bf2f(kp[a * 200]);
    ea = (hrow[tid] != tgt_i) ? __expf(acc) : 0.f;  // masked exp(score)
  }

  float wsum = ea;
  for (int off = 32; off > 0; off >>= 1) wsum += __shfl_down(wsum, off, 64);
  if (lane == 0) red[wave] = wsum;
  __syncthreads();
  float esum = red[0] + red[1] + red[2] + red[3];
  float inv = esum > 0.f ? 1.f / sqrtf(esum) : 0.f;  // exp_sum ** 0.5 (BETA)

  float part = 0.f;
  if (tid < Hn) {
    float attn = ea * inv;
    float gc = g[tid]; gc = gc > 0.f ? gc : 0.f;  // relu
    float dm = dist_mat[(size_t)i * Hn + tid];
    float geo = __expf(-dm / (gc + 1.f));
    part = (attn + geo) * sc1 + hv[tid] * sc2;
  }
  __syncthreads();  // protect red[] reuse
  for (int off = 32; off > 0; off >>= 1) part += __shfl_down(part, off, 64);
  if (lane == 0) red[wave] = part;
  __syncthreads();
  if (tid == 0) {
    float pred = red[0] + red[1] + red[2] + red[3];
    out[i] = 1.f / (1.f + __expf(-pred));
  }
}

extern "C" void kernel_launch(void* const* d_in, const int* in_sizes, int n_in,
                              void* d_out, int out_size, void* d_ws, size_t ws_size,
                              hipStream_t stream) {
  const int*   history = (const int*)d_in[0];
  const int*   target  = (const int*)d_in[1];
  const int*   hregion = (const int*)d_in[2];
  const int*   tregion = (const int*)d_in[3];
  const float* hv      = (const float*)d_in[4];
  const float* dist    = (const float*)d_in[5];
  const int*   uid     = (const int*)d_in[6];
  const float* Et      = (const float*)d_in[7];
  const float* Er      = (const float*)d_in[8];
  const float* Edist   = (const float*)d_in[9];
  const float* Wq      = (const float*)d_in[10];
  const float* Wk      = (const float*)d_in[11];
  const float* Wv      = (const float*)d_in[12];

  float* g = (float*)d_ws;                          // 200 f32 (1KB slot)
  USH* A   = (USH*)((char*)d_ws + 1024);            // 50000*128 bf16 = 12.8MB
  USH* Bt  = A + (size_t)NITEM * Dn;                // 1000*128 bf16
  USH* Ebr = Bt + (size_t)NREG * Dn;                // 50000*64 bf16 = 6.4MB
  USH* Err = Ebr + (size_t)NITEM * Dh;              // 1000*64 bf16
  size_t need_raw = 1024 + 2 * ((size_t)NITEM * Dn + (size_t)NREG * Dn +
                                (size_t)NITEM * Dh + (size_t)NREG * Dh);
  int use_raw = (ws_size >= need_raw) ? 1 : 0;
  float* out = (float*)d_out;

  hipMemsetAsync(g, 0, Hn * sizeof(float), stream);
  g_kernel<<<Bn / 16, 256, 0, stream>>>(hregion, tregion, Edist, uid, g);
  ab_kernel<<<AB_A_BLOCKS + AB_B_BLOCKS, 256, 0, stream>>>(Et, Er, Wk, A, Bt,
                                                           Ebr, Err, use_raw);
  main_kernel<<<Bn, 256, 0, stream>>>(history, target, hregion, tregion, hv, dist,
                                      Et, Er, Wq, Wv, g, A, Bt, Ebr, Err, use_raw,
                                      out);
}

// Round 10
// 172.731 us; speedup vs baseline: 1.0373x; 1.0373x over previous
//
#include <hip/hip_runtime.h>

typedef unsigned short USH;
typedef unsigned int   UIN;

static constexpr int Bn = 1024;    // batch
static constexpr int Hn = 200;     // history length
static constexpr int Dn = 128;     // embed/hidden
static constexpr int Dh = 64;      // half embed
static constexpr int NITEM = 50000;
static constexpr int NREG  = 1000;
static constexpr int MT = 64;      // items per ab block
static constexpr int AB_A_BLOCKS = (NITEM + MT - 1) / MT;  // 782
static constexpr int AB_B_BLOCKS = (NREG  + MT - 1) / MT;  // 16
static constexpr int WTS = 132;    // wt stride (floats)
static constexpr int ETS = 69;     // et stride (floats)
static constexpr int CR = 50;      // kv rows per chunk (32 a's <-> 50 rows: 32*200==50*128)

__device__ __forceinline__ float bf2f(USH u) {
  return __uint_as_float(((UIN)u) << 16);
}
__device__ __forceinline__ float2 pb2f2(UIN p) {  // packed bf16 pair -> 2 floats
  float2 r;
  r.x = __uint_as_float(p << 16);
  r.y = __uint_as_float(p & 0xffff0000u);
  return r;
}
__device__ __forceinline__ USH f2b(float f) {  // fp32 -> bf16 rne
  UIN x = __float_as_uint(f);
  return (USH)((x + 0x7fffu + ((x >> 16) & 1u)) >> 16);
}
__device__ __forceinline__ UIN addpk(UIN u, UIN v) {  // bf16x2 + bf16x2
  float2 a = pb2f2(u), b = pb2f2(v);
  return (UIN)f2b(a.x + b.x) | ((UIN)f2b(a.y + b.y) << 16);
}

// ---------------------------------------------------------------------------
// g[c] = sum_i row[tr[i]] * row[hr[i,c]],  row = embed_dist[uid]  (fp32)
// ---------------------------------------------------------------------------
__global__ __launch_bounds__(256) void g_kernel(
    const int* __restrict__ hregion, const int* __restrict__ tregion,
    const float* __restrict__ embed_dist, const int* __restrict__ uid,
    float* __restrict__ g) {
  int c = threadIdx.x;
  const float* row = embed_dist + (size_t)uid[0] * NREG;  // 4KB, L1-resident
  float acc = 0.f;
  int ibase = blockIdx.x * 16;
  for (int ii = 0; ii < 16; ii++) {
    int i = ibase + ii;
    float td = row[tregion[i]];               // wave-uniform broadcast
    if (c < Hn) acc += td * row[hregion[(size_t)i * Hn + c]];
  }
  if (c < Hn) atomicAdd(&g[c], acc);
}

// ---------------------------------------------------------------------------
// A[item][j] = dot(Et[item][0:64], Wk[j][0:64])   -> bf16 table
// B[reg][j]  = dot(Er[reg][0:64],  Wk[j][64:128]) -> bf16 table
// Register-tiled GEMM (accumulator tile 4x8 cannot be rematerialized).
// Also emits bf16 copies of the raw E rows for ep's s1/s2 gathers.
// ---------------------------------------------------------------------------
__global__ __launch_bounds__(256, 2) void ab_kernel(
    const float* __restrict__ Et, const float* __restrict__ Er,
    const float* __restrict__ Wk, USH* __restrict__ A, USH* __restrict__ Bt,
    USH* __restrict__ Ebr, USH* __restrict__ Err, int emit_raw) {
  __shared__ float wt[64 * WTS];  // 33.8KB: wt[k*WTS + j] = Wk[j][koff+k]
  __shared__ float et[MT * ETS];  // 17.7KB: et[m*ETS + k] = E[base+m][k]
  int blk = blockIdx.x, tid = threadIdx.x;
  const float* E; USH* Out; USH* OutR; int nmax, base, koff;
  if (blk < AB_A_BLOCKS) { E = Et; Out = A;  OutR = Ebr; nmax = NITEM; base = blk * MT; koff = 0; }
  else { E = Er; Out = Bt; OutR = Err; nmax = NREG; base = (blk - AB_A_BLOCKS) * MT; koff = 64; }

  // stage Wk transposed
#pragma unroll
  for (int p = 0; p < 8; p++) {
    int idx = p * 256 + tid;
    int row = idx >> 4, c4 = idx & 15;
    float4 w = *reinterpret_cast<const float4*>(Wk + (size_t)row * Dn + koff + c4 * 4);
    wt[(c4 * 4 + 0) * WTS + row] = w.x;
    wt[(c4 * 4 + 1) * WTS + row] = w.y;
    wt[(c4 * 4 + 2) * WTS + row] = w.z;
    wt[(c4 * 4 + 3) * WTS + row] = w.w;
  }
  // stage E rows row-major
#pragma unroll
  for (int p = 0; p < 4; p++) {
    int idx = p * 256 + tid;
    int m = idx >> 4, c4 = idx & 15;
    int gi = base + m;
    float4 e = make_float4(0.f, 0.f, 0.f, 0.f);
    if (gi < nmax) e = *reinterpret_cast<const float4*>(E + (size_t)gi * Dh + c4 * 4);
    et[m * ETS + c4 * 4 + 0] = e.x;
    et[m * ETS + c4 * 4 + 1] = e.y;
    et[m * ETS + c4 * 4 + 2] = e.z;
    et[m * ETS + c4 * 4 + 3] = e.w;
  }
  __syncthreads();

  // bf16 copy of raw E rows (for ep's s1/s2)
  if (emit_raw) {
#pragma unroll
    for (int q = 0; q < 8; q++) {
      int idx = q * 256 + tid;       // 0..2047
      int m = idx >> 5, kp = idx & 31;
      int gi = base + m;
      if (gi < nmax) {
        UIN pk = (UIN)f2b(et[m * ETS + 2 * kp]) | ((UIN)f2b(et[m * ETS + 2 * kp + 1]) << 16);
        *reinterpret_cast<UIN*>(OutR + (size_t)gi * Dh + 2 * kp) = pk;
      }
    }
  }

  int jt = tid & 15, it = tid >> 4;     // 8 j's, 4 items per thread
  const float* wb = wt + jt * 8;
  const float* eb = et + (it * 4) * ETS;
  float c[4][8];
#pragma unroll
  for (int ii = 0; ii < 4; ii++)
#pragma unroll
    for (int jj = 0; jj < 8; jj++) c[ii][jj] = 0.f;

#pragma unroll 2
  for (int k = 0; k < 64; k++) {
    float4 w0 = *reinterpret_cast<const float4*>(wb + (size_t)k * WTS);
    float4 w1 = *reinterpret_cast<const float4*>(wb + (size_t)k * WTS + 4);
    float e0 = eb[k], e1 = eb[ETS + k], e2 = eb[2 * ETS + k], e3 = eb[3 * ETS + k];
    c[0][0] += e0 * w0.x; c[0][1] += e0 * w0.y; c[0][2] += e0 * w0.z; c[0][3] += e0 * w0.w;
    c[0][4] += e0 * w1.x; c[0][5] += e0 * w1.y; c[0][6] += e0 * w1.z; c[0][7] += e0 * w1.w;
    c[1][0] += e1 * w0.x; c[1][1] += e1 * w0.y; c[1][2] += e1 * w0.z; c[1][3] += e1 * w0.w;
    c[1][4] += e1 * w1.x; c[1][5] += e1 * w1.y; c[1][6] += e1 * w1.z; c[1][7] += e1 * w1.w;
    c[2][0] += e2 * w0.x; c[2][1] += e2 * w0.y; c[2][2] += e2 * w0.z; c[2][3] += e2 * w0.w;
    c[2][4] += e2 * w1.x; c[2][5] += e2 * w1.y; c[2][6] += e2 * w1.z; c[2][7] += e2 * w1.w;
    c[3][0] += e3 * w0.x; c[3][1] += e3 * w0.y; c[3][2] += e3 * w0.z; c[3][3] += e3 * w0.w;
    c[3][4] += e3 * w1.x; c[3][5] += e3 * w1.y; c[3][6] += e3 * w1.z; c[3][7] += e3 * w1.w;
  }

#pragma unroll
  for (int ii = 0; ii < 4; ii++) {
    int item = base + it * 4 + ii;
    if (item < nmax) {
      uint4 pk;
      pk.x = (UIN)f2b(c[ii][0]) | ((UIN)f2b(c[ii][1]) << 16);
      pk.y = (UIN)f2b(c[ii][2]) | ((UIN)f2b(c[ii][3]) << 16);
      pk.z = (UIN)f2b(c[ii][4]) | ((UIN)f2b(c[ii][5]) << 16);
      pk.w = (UIN)f2b(c[ii][6]) | ((UIN)f2b(c[ii][7]) << 16);
      *reinterpret_cast<uint4*>(Out + (size_t)item * Dn + jt * 8) = pk;
    }
  }
}

// ---------------------------------------------------------------------------
// Partial-score kernel: 4096 blocks = (batch i) x (chunk h of 4).
// Chunk h: a in [32h,32h+32) touches exactly kv rows t in [50h,50h+50)
// (since 32*200 == 50*128). Stage 50 rows (12.8KB), compute the 32 needed
// qv values, write psc[(i*4+h)*200 + c]. Short serial chain, 11 blocks/CU.
// ---------------------------------------------------------------------------
__global__ __launch_bounds__(256, 4) void sc_kernel(
    const int* __restrict__ history, const int* __restrict__ target,
    const int* __restrict__ hregion, const int* __restrict__ tregion,
    const float* __restrict__ Et, const float* __restrict__ Er,
    const float* __restrict__ Wq, const USH* __restrict__ A,
    const USH* __restrict__ Bt, float* __restrict__ psc) {
  __shared__ USH kvs[CR * Dn];      // 12800B
  __shared__ float tgtE[128], qp[128], qv[32];
  int b = blockIdx.x, i = b >> 2, h = b & 3;
  int tid = threadIdx.x;
  const int* hrow = history + (size_t)i * Hn + CR * h;
  const int* rrow = hregion + (size_t)i * Hn + CR * h;

  if (tid < 64)       tgtE[tid] = Et[(size_t)target[i] * Dh + tid];
  else if (tid < 128) tgtE[tid] = Er[(size_t)tregion[i] * Dh + (tid - 64)];

  // stage 50 kv rows: 16 lanes x 16B per row, 16 rows/pass
  int rlane = tid & 15, rgrp = tid >> 4;
#pragma unroll
  for (int p = 0; p < 4; p++) {
    int t = p * 16 + rgrp;
    if (t < CR) {
      int ia = hrow[t], ib = rrow[t];
      uint4 av = *reinterpret_cast<const uint4*>(A  + (size_t)ia * Dn + rlane * 8);
      uint4 bv = *reinterpret_cast<const uint4*>(Bt + (size_t)ib * Dn + rlane * 8);
      uint4 pk;
      pk.x = addpk(av.x, bv.x); pk.y = addpk(av.y, bv.y);
      pk.z = addpk(av.z, bv.z); pk.w = addpk(av.w, bv.w);
      *reinterpret_cast<uint4*>(&kvs[t * Dn + rlane * 8]) = pk;
    }
  }
  __syncthreads();

  // qv[a'] for a = 32h + a', a' in [0,32): 4 threads per a (quarter dots)
  if (tid < 128) {
    int ql = tid >> 2, quarter = tid & 3;
    int a = 32 * h + ql;
    const float4* wp = reinterpret_cast<const float4*>(Wq + (size_t)a * Dn + quarter * 32);
    float acc = 0.f;
#pragma unroll
    for (int k4 = 0; k4 < 8; k4++) {
      float4 w = wp[k4];
      const float* tv = &tgtE[quarter * 32 + k4 * 4];
      acc += w.x * tv[0] + w.y * tv[1] + w.z * tv[2] + w.w * tv[3];
    }
    qp[tid] = acc;
  }
  __syncthreads();
  if (tid < 32)
    qv[tid] = (qp[4 * tid] + qp[4 * tid + 1] + qp[4 * tid + 2] + qp[4 * tid + 3])
              * 0.088388347648318447f;  // 1/sqrt(128)
  __syncthreads();

  if (tid < Hn) {
    // buffer halfword index a'*200 + c  (m - 6400h; same zero-math pattern)
    float acc = 0.f;
    const USH* kp = &kvs[tid];
#pragma unroll
    for (int a = 0; a < 32; a++) acc += qv[a] * bf2f(kp[a * 200]);
    psc[((size_t)i * 4 + h) * Hn + tid] = acc;
  }
}

// ---------------------------------------------------------------------------
// Epilogue: one block per batch row. Sum 4 score partials, uv, s1/s2 gathers,
// masked exp / beta-norm / geo, final dot + sigmoid. Tiny LDS.
// ---------------------------------------------------------------------------
__global__ __launch_bounds__(256, 4) void ep_kernel(
    const int* __restrict__ history, const int* __restrict__ target,
    const int* __restrict__ hregion, const int* __restrict__ tregion,
    const float* __restrict__ hv, const float* __restrict__ dist_mat,
    const float* __restrict__ Et, const float* __restrict__ Er,
    const float* __restrict__ Wv, const float* __restrict__ g,
    const USH* __restrict__ Ebr, const USH* __restrict__ Err,
    const float* __restrict__ psc, int use_raw, float* __restrict__ out) {
  __shared__ float tgtE[128], uv[128], red[8];
  int i = blockIdx.x, tid = threadIdx.x, lane = tid & 63, wave = tid >> 6;
  int tgt_i = target[i], tr_i = tregion[i];
  const int* hrow = history + (size_t)i * Hn;
  const int* rrow = hregion + (size_t)i * Hn;

  if (tid < 64)       tgtE[tid] = Et[(size_t)tgt_i * Dh + tid];
  else if (tid < 128) tgtE[tid] = Er[(size_t)tr_i * Dh + (tid - 64)];
  __syncthreads();

  if (tid >= 128) {  // uv[d] = sum_j Wv[j][d] * tgtE[j]
    int d = tid - 128;
    float a0 = 0.f, a1 = 0.f, a2 = 0.f, a3 = 0.f;
#pragma unroll 8
    for (int j = 0; j < 128; j += 4) {
      a0 += Wv[(size_t)(j + 0) * Dn + d] * tgtE[j + 0];
      a1 += Wv[(size_t)(j + 1) * Dn + d] * tgtE[j + 1];
      a2 += Wv[(size_t)(j + 2) * Dn + d] * tgtE[j + 2];
      a3 += Wv[(size_t)(j + 3) * Dn + d] * tgtE[j + 3];
    }
    uv[d] = (a0 + a1) + (a2 + a3);
  }
  __syncthreads();

  float ea = 0.f, sc1 = 0.f, sc2 = 0.f;
  if (tid < Hn) {
    const float* pp = psc + (size_t)i * 4 * Hn + tid;
    float s = (pp[0] + pp[Hn]) + (pp[2 * Hn] + pp[3 * Hn]);
    int ia2 = hrow[tid], ib2 = rrow[tid];
    float p1 = 0.f, p2 = 0.f;
    if (use_raw) {
      const uint4* epu = reinterpret_cast<const uint4*>(Ebr + (size_t)ia2 * Dh);
      const uint4* rpu = reinterpret_cast<const uint4*>(Err + (size_t)ib2 * Dh);
#pragma unroll
      for (int k8 = 0; k8 < 8; k8++) {
        uint4 e = epu[k8], r = rpu[k8];
        float2 e0 = pb2f2(e.x), e1 = pb2f2(e.y), e2 = pb2f2(e.z), e3 = pb2f2(e.w);
        float2 r0 = pb2f2(r.x), r1 = pb2f2(r.y), r2 = pb2f2(r.z), r3 = pb2f2(r.w);
        const float* u0 = &uv[k8 * 8];       const float* t0 = &tgtE[k8 * 8];
        const float* u1 = &uv[64 + k8 * 8];  const float* t1 = &tgtE[64 + k8 * 8];
        p1 += e0.x * u0[0] + e0.y * u0[1] + e1.x * u0[2] + e1.y * u0[3]
            + e2.x * u0[4] + e2.y * u0[5] + e3.x * u0[6] + e3.y * u0[7]
            + r0.x * u1[0] + r0.y * u1[1] + r1.x * u1[2] + r1.y * u1[3]
            + r2.x * u1[4] + r2.y * u1[5] + r3.x * u1[6] + r3.y * u1[7];
        p2 += e0.x * t0[0] + e0.y * t0[1] + e1.x * t0[2] + e1.y * t0[3]
            + e2.x * t0[4] + e2.y * t0[5] + e3.x * t0[6] + e3.y * t0[7]
            + r0.x * t1[0] + r0.y * t1[1] + r1.x * t1[2] + r1.y * t1[3]
            + r2.x * t1[4] + r2.y * t1[5] + r3.x * t1[6] + r3.y * t1[7];
      }
    } else {
      const float4* ep = reinterpret_cast<const float4*>(Et + (size_t)ia2 * Dh);
      const float4* rp = reinterpret_cast<const float4*>(Er + (size_t)ib2 * Dh);
#pragma unroll
      for (int k4 = 0; k4 < 16; k4++) {
        float4 e = ep[k4], r = rp[k4];
        const float* u0 = &uv[k4 * 4];        const float* t0 = &tgtE[k4 * 4];
        const float* u1 = &uv[64 + k4 * 4];   const float* t1 = &tgtE[64 + k4 * 4];
        p1 += e.x * u0[0] + e.y * u0[1] + e.z * u0[2] + e.w * u0[3]
            + r.x * u1[0] + r.y * u1[1] + r.z * u1[2] + r.w * u1[3];
        p2 += e.x * t0[0] + e.y * t0[1] + e.z * t0[2] + e.w * t0[3]
            + r.x * t1[0] + r.y * t1[1] + r.z * t1[2] + r.w * t1[3];
      }
    }
    sc1 = p1; sc2 = p2;
    ea = (ia2 != tgt_i) ? __expf(s) : 0.f;  // masked exp(score)
  }

  float wsum = ea;
  for (int off = 32; off > 0; off >>= 1) wsum += __shfl_down(wsum, off, 64);
  if (lane == 0) red[wave] = wsum;
  __syncthreads();
  float esum = red[0] + red[1] + red[2] + red[3];
  float inv = esum > 0.f ? 1.f / sqrtf(esum) : 0.f;  // exp_sum ** 0.5 (BETA)

  float part = 0.f;
  if (tid < Hn) {
    float attn = ea * inv;
    float gc = g[tid]; gc = gc > 0.f ? gc : 0.f;  // relu
    float dm = dist_mat[(size_t)i * Hn + tid];
    float geo = __expf(-dm / (gc + 1.f));
    part = (attn + geo) * sc1 + hv[tid] * sc2;
  }
  __syncthreads();  // protect red[] reuse
  for (int off = 32; off > 0; off >>= 1) part += __shfl_down(part, off, 64);
  if (lane == 0) red[wave] = part;
  __syncthreads();
  if (tid == 0) {
    float pred = red[0] + red[1] + red[2] + red[3];
    out[i] = 1.f / (1.f + __expf(-pred));
  }
}

extern "C" void kernel_launch(void* const* d_in, const int* in_sizes, int n_in,
                              void* d_out, int out_size, void* d_ws, size_t ws_size,
                              hipStream_t stream) {
  const int*   history = (const int*)d_in[0];
  const int*   target  = (const int*)d_in[1];
  const int*   hregion = (const int*)d_in[2];
  const int*   tregion = (const int*)d_in[3];
  const float* hv      = (const float*)d_in[4];
  const float* dist    = (const float*)d_in[5];
  const int*   uid     = (const int*)d_in[6];
  const float* Et      = (const float*)d_in[7];
  const float* Er      = (const float*)d_in[8];
  const float* Edist   = (const float*)d_in[9];
  const float* Wq      = (const float*)d_in[10];
  const float* Wk      = (const float*)d_in[11];
  const float* Wv      = (const float*)d_in[12];

  float* g = (float*)d_ws;                          // 200 f32 (1KB slot)
  USH* A   = (USH*)((char*)d_ws + 1024);            // 50000*128 bf16 = 12.8MB
  USH* Bt  = A + (size_t)NITEM * Dn;                // 1000*128 bf16
  USH* Ebr = Bt + (size_t)NREG * Dn;                // 50000*64 bf16 = 6.4MB
  USH* Err = Ebr + (size_t)NITEM * Dh;              // 1000*64 bf16
  float* psc = (float*)(Err + (size_t)NREG * Dh);   // 1024*4*200 f32 = 3.2MB
  size_t need_raw = 1024 + 2 * ((size_t)NITEM * Dn + (size_t)NREG * Dn +
                                (size_t)NITEM * Dh + (size_t)NREG * Dh) +
                    4 * (size_t)Bn * 4 * Hn;
  int use_raw = (ws_size >= need_raw) ? 1 : 0;
  float* out = (float*)d_out;

  hipMemsetAsync(g, 0, Hn * sizeof(float), stream);
  g_kernel<<<Bn / 16, 256, 0, stream>>>(hregion, tregion, Edist, uid, g);
  ab_kernel<<<AB_A_BLOCKS + AB_B_BLOCKS, 256, 0, stream>>>(Et, Er, Wk, A, Bt,
                                                           Ebr, Err, use_raw);
  sc_kernel<<<Bn * 4, 256, 0, stream>>>(history, target, hregion, tregion,
                                        Et, Er, Wq, A, Bt, psc);
  ep_kernel<<<Bn, 256, 0, stream>>>(history, target, hregion, tregion, hv, dist,
                                    Et, Er, Wv, g, Ebr, Err, psc, use_raw, out);
}

// Round 11
// 160.161 us; speedup vs baseline: 1.1188x; 1.0785x over previous
//
#include <hip/hip_runtime.h>

typedef unsigned short USH;
typedef unsigned int   UIN;

static constexpr int Bn = 1024;    // batch
static constexpr int Hn = 200;     // history length
static constexpr int Dn = 128;     // embed/hidden
static constexpr int Dh = 64;      // half embed
static constexpr int NITEM = 50000;
static constexpr int NREG  = 1000;
static constexpr int MT = 64;      // items per ab block
static constexpr int AB_A_BLOCKS = (NITEM + MT - 1) / MT;  // 782
static constexpr int AB_B_BLOCKS = (NREG  + MT - 1) / MT;  // 16
static constexpr int AB_TOT = AB_A_BLOCKS + AB_B_BLOCKS;   // 798
static constexpr int QU_BLOCKS = Bn / 4;                   // 256 (4 rows/block)
static constexpr int WTS = 132;    // wt stride (floats)
static constexpr int ETS = 69;     // et stride (floats)
static constexpr int CR  = 50;     // kv rows per chunk (32*200 == 50*128)
static constexpr int AFS = 192;    // fused row: 128 kv-proj + 64 raw (bf16)

__device__ __forceinline__ float bf2f(USH u) {
  return __uint_as_float(((UIN)u) << 16);
}
__device__ __forceinline__ float2 pb2f2(UIN p) {  // packed bf16 pair -> 2 floats
  float2 r;
  r.x = __uint_as_float(p << 16);
  r.y = __uint_as_float(p & 0xffff0000u);
  return r;
}
__device__ __forceinline__ USH f2b(float f) {  // fp32 -> bf16 rne
  UIN x = __float_as_uint(f);
  return (USH)((x + 0x7fffu + ((x >> 16) & 1u)) >> 16);
}
__device__ __forceinline__ UIN addpk(UIN u, UIN v) {  // bf16x2 + bf16x2
  float2 a = pb2f2(u), b = pb2f2(v);
  return (UIN)f2b(a.x + b.x) | ((UIN)f2b(a.y + b.y) << 16);
}

// ---------------------------------------------------------------------------
// g[c] = sum_i row[tr[i]] * row[hr[i,c]],  row = embed_dist[uid]  (fp32)
// ---------------------------------------------------------------------------
__global__ __launch_bounds__(256) void g_kernel(
    const int* __restrict__ hregion, const int* __restrict__ tregion,
    const float* __restrict__ embed_dist, const int* __restrict__ uid,
    float* __restrict__ g) {
  int c = threadIdx.x;
  const float* row = embed_dist + (size_t)uid[0] * NREG;  // 4KB, L1-resident
  float acc = 0.f;
  int ibase = blockIdx.x * 16;
  for (int ii = 0; ii < 16; ii++) {
    int i = ibase + ii;
    float td = row[tregion[i]];               // wave-uniform broadcast
    if (c < Hn) acc += td * row[hregion[(size_t)i * Hn + c]];
  }
  if (c < Hn) atomicAdd(&g[c], acc);
}

// ---------------------------------------------------------------------------
// Blocks [0, AB_TOT): fused tables.
//   Af[item][0:128]   = A row   = Et[item] . Wk[:, 0:64]^T   (bf16)
//   Af[item][128:192] = raw Et[item] (bf16)
//   Bf[reg] likewise with Wk[:, 64:128] and Er.
// Register-tiled GEMM (4x8 accumulator tile cannot be rematerialized).
// Blocks [AB_TOT, AB_TOT+QU_BLOCKS): qv/uv precompute, 4 batch rows/block:
//   qvt[i][j] = (1/sqrt(128)) dot(Wq[j], tgtE_i);  uvt[i][d] = sum_j Wv[j][d] tgtE_i[j]
// ---------------------------------------------------------------------------
__global__ __launch_bounds__(256, 2) void ab_kernel(
    const float* __restrict__ Et, const float* __restrict__ Er,
    const float* __restrict__ Wk, const float* __restrict__ Wq,
    const float* __restrict__ Wv, const int* __restrict__ target,
    const int* __restrict__ tregion,
    USH* __restrict__ Af, USH* __restrict__ Bf,
    float* __restrict__ qvt, float* __restrict__ uvt) {
  __shared__ float wt[64 * WTS];  // 33.8KB (qu path reuses as te[4][128])
  __shared__ float et[MT * ETS];  // 17.7KB
  int blk = blockIdx.x, tid = threadIdx.x;

  if (blk >= AB_TOT) {
    // ---------------- qv/uv precompute path ----------------
    float* te = wt;  // te[ii*128 + d], 4 target-embed rows
    int i0 = (blk - AB_TOT) * 4;
#pragma unroll
    for (int v = 0; v < 2; v++) {
      int idx = v * 256 + tid;      // 0..511
      int ii = idx >> 7, d = idx & 127;
      int it = i0 + ii;
      te[ii * 128 + d] = (d < 64) ? Et[(size_t)target[it] * Dh + d]
                                  : Er[(size_t)tregion[it] * Dh + (d - 64)];
    }
    __syncthreads();
    int j = tid & 127, half = tid >> 7;
    float a0 = 0.f, a1 = 0.f, a2 = 0.f, a3 = 0.f;
    if (half == 0) {  // qv: thread j owns Wq row j, 4 batch rows at once
      const float* wr = Wq + (size_t)j * Dn;
#pragma unroll 8
      for (int k = 0; k < 128; k++) {
        float w = wr[k];
        a0 += w * te[k]; a1 += w * te[128 + k];
        a2 += w * te[256 + k]; a3 += w * te[384 + k];
      }
      const float s = 0.088388347648318447f;  // 1/sqrt(128)
      qvt[(size_t)(i0 + 0) * Dn + j] = a0 * s;
      qvt[(size_t)(i0 + 1) * Dn + j] = a1 * s;
      qvt[(size_t)(i0 + 2) * Dn + j] = a2 * s;
      qvt[(size_t)(i0 + 3) * Dn + j] = a3 * s;
    } else {          // uv: column sweep, coalesced across d
      int d = j;
#pragma unroll 8
      for (int k = 0; k < 128; k++) {
        float w = Wv[(size_t)k * Dn + d];
        a0 += w * te[k]; a1 += w * te[128 + k];
        a2 += w * te[256 + k]; a3 += w * te[384 + k];
      }
      uvt[(size_t)(i0 + 0) * Dn + d] = a0;
      uvt[(size_t)(i0 + 1) * Dn + d] = a1;
      uvt[(size_t)(i0 + 2) * Dn + d] = a2;
      uvt[(size_t)(i0 + 3) * Dn + d] = a3;
    }
    return;
  }

  // ---------------- fused-table GEMM path ----------------
  const float* E; USH* Out; int nmax, base, koff;
  if (blk < AB_A_BLOCKS) { E = Et; Out = Af; nmax = NITEM; base = blk * MT; koff = 0; }
  else { E = Er; Out = Bf; nmax = NREG; base = (blk - AB_A_BLOCKS) * MT; koff = 64; }

  // stage Wk transposed
#pragma unroll
  for (int p = 0; p < 8; p++) {
    int idx = p * 256 + tid;
    int row = idx >> 4, c4 = idx & 15;
    float4 w = *reinterpret_cast<const float4*>(Wk + (size_t)row * Dn + koff + c4 * 4);
    wt[(c4 * 4 + 0) * WTS + row] = w.x;
    wt[(c4 * 4 + 1) * WTS + row] = w.y;
    wt[(c4 * 4 + 2) * WTS + row] = w.z;
    wt[(c4 * 4 + 3) * WTS + row] = w.w;
  }
  // stage E rows row-major
#pragma unroll
  for (int p = 0; p < 4; p++) {
    int idx = p * 256 + tid;
    int m = idx >> 4, c4 = idx & 15;
    int gi = base + m;
    float4 e = make_float4(0.f, 0.f, 0.f, 0.f);
    if (gi < nmax) e = *reinterpret_cast<const float4*>(E + (size_t)gi * Dh + c4 * 4);
    et[m * ETS + c4 * 4 + 0] = e.x;
    et[m * ETS + c4 * 4 + 1] = e.y;
    et[m * ETS + c4 * 4 + 2] = e.z;
    et[m * ETS + c4 * 4 + 3] = e.w;
  }
  __syncthreads();

  // raw-half emit: Af[item][128 + 2kp .. ] = bf16(E row)
#pragma unroll
  for (int q = 0; q < 8; q++) {
    int idx = q * 256 + tid;       // 0..2047
    int m = idx >> 5, kp = idx & 31;
    int gi = base + m;
    if (gi < nmax) {
      UIN pk = (UIN)f2b(et[m * ETS + 2 * kp]) | ((UIN)f2b(et[m * ETS + 2 * kp + 1]) << 16);
      *reinterpret_cast<UIN*>(Out + (size_t)gi * AFS + 128 + 2 * kp) = pk;
    }
  }

  int jt = tid & 15, it = tid >> 4;     // 8 j's, 4 items per thread
  const float* wb = wt + jt * 8;
  const float* eb = et + (it * 4) * ETS;
  float c[4][8];
#pragma unroll
  for (int ii = 0; ii < 4; ii++)
#pragma unroll
    for (int jj = 0; jj < 8; jj++) c[ii][jj] = 0.f;

#pragma unroll 2
  for (int k = 0; k < 64; k++) {
    float4 w0 = *reinterpret_cast<const float4*>(wb + (size_t)k * WTS);
    float4 w1 = *reinterpret_cast<const float4*>(wb + (size_t)k * WTS + 4);
    float e0 = eb[k], e1 = eb[ETS + k], e2 = eb[2 * ETS + k], e3 = eb[3 * ETS + k];
    c[0][0] += e0 * w0.x; c[0][1] += e0 * w0.y; c[0][2] += e0 * w0.z; c[0][3] += e0 * w0.w;
    c[0][4] += e0 * w1.x; c[0][5] += e0 * w1.y; c[0][6] += e0 * w1.z; c[0][7] += e0 * w1.w;
    c[1][0] += e1 * w0.x; c[1][1] += e1 * w0.y; c[1][2] += e1 * w0.z; c[1][3] += e1 * w0.w;
    c[1][4] += e1 * w1.x; c[1][5] += e1 * w1.y; c[1][6] += e1 * w1.z; c[1][7] += e1 * w1.w;
    c[2][0] += e2 * w0.x; c[2][1] += e2 * w0.y; c[2][2] += e2 * w0.z; c[2][3] += e2 * w0.w;
    c[2][4] += e2 * w1.x; c[2][5] += e2 * w1.y; c[2][6] += e2 * w1.z; c[2][7] += e2 * w1.w;
    c[3][0] += e3 * w0.x; c[3][1] += e3 * w0.y; c[3][2] += e3 * w0.z; c[3][3] += e3 * w0.w;
    c[3][4] += e3 * w1.x; c[3][5] += e3 * w1.y; c[3][6] += e3 * w1.z; c[3][7] += e3 * w1.w;
  }

#pragma unroll
  for (int ii = 0; ii < 4; ii++) {
    int item = base + it * 4 + ii;
    if (item < nmax) {
      uint4 pk;
      pk.x = (UIN)f2b(c[ii][0]) | ((UIN)f2b(c[ii][1]) << 16);
      pk.y = (UIN)f2b(c[ii][2]) | ((UIN)f2b(c[ii][3]) << 16);
      pk.z = (UIN)f2b(c[ii][4]) | ((UIN)f2b(c[ii][5]) << 16);
      pk.w = (UIN)f2b(c[ii][6]) | ((UIN)f2b(c[ii][7]) << 16);
      *reinterpret_cast<uint4*>(Out + (size_t)item * AFS + jt * 8) = pk;
    }
  }
}

// ---------------------------------------------------------------------------
// Partial scores + s1/s2: 4096 blocks = (batch i) x (chunk h of 4).
// Chunk h: a in [32h,32h+32) <-> kv rows t in [50h,50h+50). Gathers the fused
// 384B rows once: kv half -> LDS score buffer; raw half -> register dot for
// s1[t]=dot(hist_emb,uv), s2[t]=dot(hist_emb,tgtE) (8-lane shuffle reduce).
// ---------------------------------------------------------------------------
__global__ __launch_bounds__(256, 4) void sc_kernel(
    const int* __restrict__ history, const int* __restrict__ target,
    const int* __restrict__ hregion, const int* __restrict__ tregion,
    const float* __restrict__ Et, const float* __restrict__ Er,
    const float* __restrict__ qvt, const float* __restrict__ uvt,
    const USH* __restrict__ Af, const USH* __restrict__ Bf,
    float* __restrict__ psc, float2* __restrict__ s12) {
  __shared__ USH kvs[CR * Dn];      // 12800B
  __shared__ float tgtE[128], uvf[128], qv[32];
  int b = blockIdx.x, i = b >> 2, h = b & 3;
  int tid = threadIdx.x;
  const int* hrow = history + (size_t)i * Hn + CR * h;
  const int* rrow = hregion + (size_t)i * Hn + CR * h;

  if (tid < 128) {
    tgtE[tid] = (tid < 64) ? Et[(size_t)target[i] * Dh + tid]
                           : Er[(size_t)tregion[i] * Dh + (tid - 64)];
  } else {
    uvf[tid - 128] = uvt[(size_t)i * Dn + (tid - 128)];
  }
  if (tid < 32) qv[tid] = qvt[(size_t)i * Dn + 32 * h + tid];

  // stage kv halves: 16 lanes x 16B per row
  {
    int rlane = tid & 15, rgrp = tid >> 4;
#pragma unroll
    for (int p = 0; p < 4; p++) {
      int t = p * 16 + rgrp;
      if (t < CR) {
        int ia = hrow[t], ib = rrow[t];
        uint4 av = *reinterpret_cast<const uint4*>(Af + (size_t)ia * AFS + rlane * 8);
        uint4 bv = *reinterpret_cast<const uint4*>(Bf + (size_t)ib * AFS + rlane * 8);
        uint4 pk;
        pk.x = addpk(av.x, bv.x); pk.y = addpk(av.y, bv.y);
        pk.z = addpk(av.z, bv.z); pk.w = addpk(av.w, bv.w);
        *reinterpret_cast<uint4*>(&kvs[t * Dn + rlane * 8]) = pk;
      }
    }
  }
  __syncthreads();  // tgtE/uvf ready for raw dots; kvs ready for scores

  // raw halves -> s1/s2: 8 lanes x 16B per row, 32 rows/pass
  {
    int l8 = tid & 7, r8 = tid >> 3;
#pragma unroll
    for (int p = 0; p < 2; p++) {
      int t = p * 32 + r8;
      if (t < CR) {
        int ia = hrow[t], ib = rrow[t];
        uint4 e = *reinterpret_cast<const uint4*>(Af + (size_t)ia * AFS + 128 + l8 * 8);
        uint4 r = *reinterpret_cast<const uint4*>(Bf + (size_t)ib * AFS + 128 + l8 * 8);
        float2 e0 = pb2f2(e.x), e1 = pb2f2(e.y), e2 = pb2f2(e.z), e3 = pb2f2(e.w);
        float2 r0 = pb2f2(r.x), r1 = pb2f2(r.y), r2 = pb2f2(r.z), r3 = pb2f2(r.w);
        const float* u0 = &uvf[l8 * 8];       const float* t0 = &tgtE[l8 * 8];
        const float* u1 = &uvf[64 + l8 * 8];  const float* t1 = &tgtE[64 + l8 * 8];
        float s1a = e0.x * u0[0] + e0.y * u0[1] + e1.x * u0[2] + e1.y * u0[3]
                  + e2.x * u0[4] + e2.y * u0[5] + e3.x * u0[6] + e3.y * u0[7]
                  + r0.x * u1[0] + r0.y * u1[1] + r1.x * u1[2] + r1.y * u1[3]
                  + r2.x * u1[4] + r2.y * u1[5] + r3.x * u1[6] + r3.y * u1[7];
        float s2a = e0.x * t0[0] + e0.y * t0[1] + e1.x * t0[2] + e1.y * t0[3]
                  + e2.x * t0[4] + e2.y * t0[5] + e3.x * t0[6] + e3.y * t0[7]
                  + r0.x * t1[0] + r0.y * t1[1] + r1.x * t1[2] + r1.y * t1[3]
                  + r2.x * t1[4] + r2.y * t1[5] + r3.x * t1[6] + r3.y * t1[7];
        s1a += __shfl_xor(s1a, 1, 64); s2a += __shfl_xor(s2a, 1, 64);
        s1a += __shfl_xor(s1a, 2, 64); s2a += __shfl_xor(s2a, 2, 64);
        s1a += __shfl_xor(s1a, 4, 64); s2a += __shfl_xor(s2a, 4, 64);
        if (l8 == 0) s12[(size_t)i * Hn + CR * h + t] = make_float2(s1a, s2a);
      }
    }
  }

  // scores: buffer halfword index a'*200 + c (zero address math)
  if (tid < Hn) {
    float acc = 0.f;
    const USH* kp = &kvs[tid];
#pragma unroll
    for (int a = 0; a < 32; a++) acc += qv[a] * bf2f(kp[a * 200]);
    psc[((size_t)i * 4 + h) * Hn + tid] = acc;
  }
}

// ---------------------------------------------------------------------------
// Epilogue: one block per batch row. Fully coalesced — no gathers.
// ---------------------------------------------------------------------------
__global__ __launch_bounds__(256, 8) void ep_kernel(
    const int* __restrict__ history, const int* __restrict__ target,
    const float* __restrict__ hv, const float* __restrict__ dist_mat,
    const float* __restrict__ g, const float* __restrict__ psc,
    const float2* __restrict__ s12, float* __restrict__ out) {
  __shared__ float red[8];
  int i = blockIdx.x, tid = threadIdx.x, lane = tid & 63, wave = tid >> 6;
  int tgt_i = target[i];

  float ea = 0.f; float2 sv = make_float2(0.f, 0.f);
  if (tid < Hn) {
    const float* pp = psc + (size_t)i * 4 * Hn + tid;
    float s = (pp[0] + pp[Hn]) + (pp[2 * Hn] + pp[3 * Hn]);
    sv = s12[(size_t)i * Hn + tid];
    ea = (history[(size_t)i * Hn + tid] != tgt_i) ? __expf(s) : 0.f;
  }
  float wsum = ea;
  for (int off = 32; off > 0; off >>= 1) wsum += __shfl_down(wsum, off, 64);
  if (lane == 0) red[wave] = wsum;
  __syncthreads();
  float esum = red[0] + red[1] + red[2] + red[3];
  float inv = esum > 0.f ? 1.f / sqrtf(esum) : 0.f;  // exp_sum ** 0.5 (BETA)

  float part = 0.f;
  if (tid < Hn) {
    float gc = g[tid]; gc = gc > 0.f ? gc : 0.f;  // relu
    float dm = dist_mat[(size_t)i * Hn + tid];
    float geo = __expf(-dm / (gc + 1.f));
    part = (ea * inv + geo) * sv.x + hv[tid] * sv.y;
  }
  __syncthreads();  // protect red[] reuse
  for (int off = 32; off > 0; off >>= 1) part += __shfl_down(part, off, 64);
  if (lane == 0) red[wave] = part;
  __syncthreads();
  if (tid == 0) {
    float pred = red[0] + red[1] + red[2] + red[3];
    out[i] = 1.f / (1.f + __expf(-pred));
  }
}

extern "C" void kernel_launch(void* const* d_in, const int* in_sizes, int n_in,
                              void* d_out, int out_size, void* d_ws, size_t ws_size,
                              hipStream_t stream) {
  const int*   history = (const int*)d_in[0];
  const int*   target  = (const int*)d_in[1];
  const int*   hregion = (const int*)d_in[2];
  const int*   tregion = (const int*)d_in[3];
  const float* hv      = (const float*)d_in[4];
  const float* dist    = (const float*)d_in[5];
  const int*   uid     = (const int*)d_in[6];
  const float* Et      = (const float*)d_in[7];
  const float* Er      = (const float*)d_in[8];
  const float* Edist   = (const float*)d_in[9];
  const float* Wq      = (const float*)d_in[10];
  const float* Wk      = (const float*)d_in[11];
  const float* Wv      = (const float*)d_in[12];

  char* w = (char*)d_ws;
  float* g   = (float*)w;                            // 1KB slot
  USH*   Af  = (USH*)(w + 1024);                     // 50000*192 bf16 = 19.2MB
  USH*   Bf  = Af + (size_t)NITEM * AFS;             // 1000*192 bf16 = 384KB
  float* qvt = (float*)(Bf + (size_t)NREG * AFS);    // 1024*128 f32 = 512KB
  float* uvt = qvt + (size_t)Bn * Dn;                // 512KB
  float* psc = uvt + (size_t)Bn * Dn;                // 1024*4*200 f32 = 3.2MB
  float2* s12 = (float2*)(psc + (size_t)Bn * 4 * Hn);// 1024*200 float2 = 1.6MB
  float* out = (float*)d_out;

  hipMemsetAsync(g, 0, Hn * sizeof(float), stream);
  g_kernel<<<Bn / 16, 256, 0, stream>>>(hregion, tregion, Edist, uid, g);
  ab_kernel<<<AB_TOT + QU_BLOCKS, 256, 0, stream>>>(Et, Er, Wk, Wq, Wv, target,
                                                    tregion, Af, Bf, qvt, uvt);
  sc_kernel<<<Bn * 4, 256, 0, stream>>>(history, target, hregion, tregion,
                                        Et, Er, qvt, uvt, Af, Bf, psc, s12);
  ep_kernel<<<Bn, 256, 0, stream>>>(history, target, hv, dist, g, psc, s12, out);
}

// Round 12
// 153.945 us; speedup vs baseline: 1.1639x; 1.0404x over previous
//
#include <hip/hip_runtime.h>

typedef unsigned short USH;
typedef unsigned int   UIN;

static constexpr int Bn = 1024;    // batch
static constexpr int Hn = 200;     // history length
static constexpr int Dn = 128;     // embed/hidden
static constexpr int Dh = 64;      // half embed
static constexpr int NITEM = 50000;
static constexpr int NREG  = 1000;
static constexpr int MT = 64;      // items per ab block
static constexpr int AB_A_BLOCKS = (NITEM + MT - 1) / MT;  // 782
static constexpr int AB_B_BLOCKS = (NREG  + MT - 1) / MT;  // 16
static constexpr int AB_TOT = AB_A_BLOCKS + AB_B_BLOCKS;   // 798
static constexpr int QU_BLOCKS = Bn / 4;                   // 256 (4 rows/block)
static constexpr int G_BLOCKS  = Bn / 16;                  // 64  (16 rows/block)
static constexpr int WTS = 132;    // wt stride (floats)
static constexpr int ETS = 69;     // et stride (floats)
static constexpr int CR  = 50;     // kv rows per chunk (32*200 == 50*128)
static constexpr int AFS = 192;    // fused row: 128 kv-proj + 64 raw (bf16)

__device__ __forceinline__ float bf2f(USH u) {
  return __uint_as_float(((UIN)u) << 16);
}
__device__ __forceinline__ float2 pb2f2(UIN p) {  // packed bf16 pair -> 2 floats
  float2 r;
  r.x = __uint_as_float(p << 16);
  r.y = __uint_as_float(p & 0xffff0000u);
  return r;
}
__device__ __forceinline__ USH f2b(float f) {  // fp32 -> bf16 rne
  UIN x = __float_as_uint(f);
  return (USH)((x + 0x7fffu + ((x >> 16) & 1u)) >> 16);
}
__device__ __forceinline__ UIN addpk(UIN u, UIN v) {  // bf16x2 + bf16x2
  float2 a = pb2f2(u), b = pb2f2(v);
  return (UIN)f2b(a.x + b.x) | ((UIN)f2b(a.y + b.y) << 16);
}

// ---------------------------------------------------------------------------
// ab_kernel grid = [table GEMM | qv/uv precompute | g accumulate]
//   Af[item][0:128] = Et[item].Wk[:,0:64]^T (bf16); [128:192] = raw Et (bf16)
//   Bf[reg] likewise (Wk[:,64:128], Er).
//   qvt[i][j] = (1/sqrt128) dot(Wq[j], tgtE_i);  uvt[i][d] = sum_j Wv[j][d] tgtE_i[j]
//   g[c] += sum_i row[tr[i]]*row[hr[i,c]]  (row = embed_dist[uid]; g pre-zeroed)
// ---------------------------------------------------------------------------
__global__ __launch_bounds__(256, 2) void ab_kernel(
    const float* __restrict__ Et, const float* __restrict__ Er,
    const float* __restrict__ Wk, const float* __restrict__ Wq,
    const float* __restrict__ Wv, const int* __restrict__ target,
    const int* __restrict__ tregion, const int* __restrict__ hregion,
    const float* __restrict__ embed_dist, const int* __restrict__ uid,
    USH* __restrict__ Af, USH* __restrict__ Bf,
    float* __restrict__ qvt, float* __restrict__ uvt, float* __restrict__ g) {
  __shared__ float wt[64 * WTS];  // 33.8KB (qu path reuses as te[4][128])
  __shared__ float et[MT * ETS];  // 17.7KB
  int blk = blockIdx.x, tid = threadIdx.x;

  if (blk >= AB_TOT + QU_BLOCKS) {
    // ---------------- g-accumulate path (64 blocks x 16 rows) ----------------
    int c = tid;
    const float* row = embed_dist + (size_t)uid[0] * NREG;  // 4KB, L1-resident
    float acc = 0.f;
    int ibase = (blk - AB_TOT - QU_BLOCKS) * 16;
    for (int ii = 0; ii < 16; ii++) {
      int i = ibase + ii;
      float td = row[tregion[i]];             // wave-uniform broadcast
      if (c < Hn) acc += td * row[hregion[(size_t)i * Hn + c]];
    }
    if (c < Hn) atomicAdd(&g[c], acc);
    return;
  }

  if (blk >= AB_TOT) {
    // ---------------- qv/uv precompute path ----------------
    float* te = wt;  // te[ii*128 + d], 4 target-embed rows
    int i0 = (blk - AB_TOT) * 4;
#pragma unroll
    for (int v = 0; v < 2; v++) {
      int idx = v * 256 + tid;      // 0..511
      int ii = idx >> 7, d = idx & 127;
      int it = i0 + ii;
      te[ii * 128 + d] = (d < 64) ? Et[(size_t)target[it] * Dh + d]
                                  : Er[(size_t)tregion[it] * Dh + (d - 64)];
    }
    __syncthreads();
    int j = tid & 127, half = tid >> 7;
    float a0 = 0.f, a1 = 0.f, a2 = 0.f, a3 = 0.f;
    if (half == 0) {  // qv: thread j owns Wq row j, 4 batch rows at once
      const float* wr = Wq + (size_t)j * Dn;
#pragma unroll 8
      for (int k = 0; k < 128; k++) {
        float w = wr[k];
        a0 += w * te[k]; a1 += w * te[128 + k];
        a2 += w * te[256 + k]; a3 += w * te[384 + k];
      }
      const float s = 0.088388347648318447f;  // 1/sqrt(128)
      qvt[(size_t)(i0 + 0) * Dn + j] = a0 * s;
      qvt[(size_t)(i0 + 1) * Dn + j] = a1 * s;
      qvt[(size_t)(i0 + 2) * Dn + j] = a2 * s;
      qvt[(size_t)(i0 + 3) * Dn + j] = a3 * s;
    } else {          // uv: column sweep, coalesced across d
      int d = j;
#pragma unroll 8
      for (int k = 0; k < 128; k++) {
        float w = Wv[(size_t)k * Dn + d];
        a0 += w * te[k]; a1 += w * te[128 + k];
        a2 += w * te[256 + k]; a3 += w * te[384 + k];
      }
      uvt[(size_t)(i0 + 0) * Dn + d] = a0;
      uvt[(size_t)(i0 + 1) * Dn + d] = a1;
      uvt[(size_t)(i0 + 2) * Dn + d] = a2;
      uvt[(size_t)(i0 + 3) * Dn + d] = a3;
    }
    return;
  }

  // ---------------- fused-table GEMM path ----------------
  const float* E; USH* Out; int nmax, base, koff;
  if (blk < AB_A_BLOCKS) { E = Et; Out = Af; nmax = NITEM; base = blk * MT; koff = 0; }
  else { E = Er; Out = Bf; nmax = NREG; base = (blk - AB_A_BLOCKS) * MT; koff = 64; }

  // stage Wk transposed
#pragma unroll
  for (int p = 0; p < 8; p++) {
    int idx = p * 256 + tid;
    int row = idx >> 4, c4 = idx & 15;
    float4 w = *reinterpret_cast<const float4*>(Wk + (size_t)row * Dn + koff + c4 * 4);
    wt[(c4 * 4 + 0) * WTS + row] = w.x;
    wt[(c4 * 4 + 1) * WTS + row] = w.y;
    wt[(c4 * 4 + 2) * WTS + row] = w.z;
    wt[(c4 * 4 + 3) * WTS + row] = w.w;
  }
  // stage E rows row-major
#pragma unroll
  for (int p = 0; p < 4; p++) {
    int idx = p * 256 + tid;
    int m = idx >> 4, c4 = idx & 15;
    int gi = base + m;
    float4 e = make_float4(0.f, 0.f, 0.f, 0.f);
    if (gi < nmax) e = *reinterpret_cast<const float4*>(E + (size_t)gi * Dh + c4 * 4);
    et[m * ETS + c4 * 4 + 0] = e.x;
    et[m * ETS + c4 * 4 + 1] = e.y;
    et[m * ETS + c4 * 4 + 2] = e.z;
    et[m * ETS + c4 * 4 + 3] = e.w;
  }
  __syncthreads();

  // raw-half emit: Out[item][128 + 2kp ..] = bf16(E row)
#pragma unroll
  for (int q = 0; q < 8; q++) {
    int idx = q * 256 + tid;       // 0..2047
    int m = idx >> 5, kp = idx & 31;
    int gi = base + m;
    if (gi < nmax) {
      UIN pk = (UIN)f2b(et[m * ETS + 2 * kp]) | ((UIN)f2b(et[m * ETS + 2 * kp + 1]) << 16);
      *reinterpret_cast<UIN*>(Out + (size_t)gi * AFS + 128 + 2 * kp) = pk;
    }
  }

  int jt = tid & 15, it = tid >> 4;     // 8 j's, 4 items per thread
  const float* wb = wt + jt * 8;
  const float* eb = et + (it * 4) * ETS;
  float c[4][8];
#pragma unroll
  for (int ii = 0; ii < 4; ii++)
#pragma unroll
    for (int jj = 0; jj < 8; jj++) c[ii][jj] = 0.f;

#pragma unroll 2
  for (int k = 0; k < 64; k++) {
    float4 w0 = *reinterpret_cast<const float4*>(wb + (size_t)k * WTS);
    float4 w1 = *reinterpret_cast<const float4*>(wb + (size_t)k * WTS + 4);
    float e0 = eb[k], e1 = eb[ETS + k], e2 = eb[2 * ETS + k], e3 = eb[3 * ETS + k];
    c[0][0] += e0 * w0.x; c[0][1] += e0 * w0.y; c[0][2] += e0 * w0.z; c[0][3] += e0 * w0.w;
    c[0][4] += e0 * w1.x; c[0][5] += e0 * w1.y; c[0][6] += e0 * w1.z; c[0][7] += e0 * w1.w;
    c[1][0] += e1 * w0.x; c[1][1] += e1 * w0.y; c[1][2] += e1 * w0.z; c[1][3] += e1 * w0.w;
    c[1][4] += e1 * w1.x; c[1][5] += e1 * w1.y; c[1][6] += e1 * w1.z; c[1][7] += e1 * w1.w;
    c[2][0] += e2 * w0.x; c[2][1] += e2 * w0.y; c[2][2] += e2 * w0.z; c[2][3] += e2 * w0.w;
    c[2][4] += e2 * w1.x; c[2][5] += e2 * w1.y; c[2][6] += e2 * w1.z; c[2][7] += e2 * w1.w;
    c[3][0] += e3 * w0.x; c[3][1] += e3 * w0.y; c[3][2] += e3 * w0.z; c[3][3] += e3 * w0.w;
    c[3][4] += e3 * w1.x; c[3][5] += e3 * w1.y; c[3][6] += e3 * w1.z; c[3][7] += e3 * w1.w;
  }

#pragma unroll
  for (int ii = 0; ii < 4; ii++) {
    int item = base + it * 4 + ii;
    if (item < nmax) {
      uint4 pk;
      pk.x = (UIN)f2b(c[ii][0]) | ((UIN)f2b(c[ii][1]) << 16);
      pk.y = (UIN)f2b(c[ii][2]) | ((UIN)f2b(c[ii][3]) << 16);
      pk.z = (UIN)f2b(c[ii][4]) | ((UIN)f2b(c[ii][5]) << 16);
      pk.w = (UIN)f2b(c[ii][6]) | ((UIN)f2b(c[ii][7]) << 16);
      *reinterpret_cast<uint4*>(Out + (size_t)item * AFS + jt * 8) = pk;
    }
  }
}

// ---------------------------------------------------------------------------
// Partial scores + s1/s2: 4096 blocks = (batch i) x (chunk h of 4).
// v12: raw-half uint4s PREFETCHED into registers before the barrier, so all
// gather loads (kv staging + raw) are in flight concurrently; dots run
// post-barrier from registers. Same bytes, deeper MLP.
// ---------------------------------------------------------------------------
__global__ __launch_bounds__(256, 4) void sc_kernel(
    const int* __restrict__ history, const int* __restrict__ target,
    const int* __restrict__ hregion, const int* __restrict__ tregion,
    const float* __restrict__ Et, const float* __restrict__ Er,
    const float* __restrict__ qvt, const float* __restrict__ uvt,
    const USH* __restrict__ Af, const USH* __restrict__ Bf,
    float* __restrict__ psc, float2* __restrict__ s12) {
  __shared__ USH kvs[CR * Dn];      // 12800B
  __shared__ float tgtE[128], uvf[128], qv[32];
  int b = blockIdx.x, i = b >> 2, h = b & 3;
  int tid = threadIdx.x;
  const int* hrow = history + (size_t)i * Hn + CR * h;
  const int* rrow = hregion + (size_t)i * Hn + CR * h;

  if (tid < 128) {
    tgtE[tid] = (tid < 64) ? Et[(size_t)target[i] * Dh + tid]
                           : Er[(size_t)tregion[i] * Dh + (tid - 64)];
  } else {
    uvf[tid - 128] = uvt[(size_t)i * Dn + (tid - 128)];
  }
  if (tid < 32) qv[tid] = qvt[(size_t)i * Dn + 32 * h + tid];

  // stage kv halves: 16 lanes x 16B per row
  {
    int rlane = tid & 15, rgrp = tid >> 4;
#pragma unroll
    for (int p = 0; p < 4; p++) {
      int t = p * 16 + rgrp;
      if (t < CR) {
        int ia = hrow[t], ib = rrow[t];
        uint4 av = *reinterpret_cast<const uint4*>(Af + (size_t)ia * AFS + rlane * 8);
        uint4 bv = *reinterpret_cast<const uint4*>(Bf + (size_t)ib * AFS + rlane * 8);
        uint4 pk;
        pk.x = addpk(av.x, bv.x); pk.y = addpk(av.y, bv.y);
        pk.z = addpk(av.z, bv.z); pk.w = addpk(av.w, bv.w);
        *reinterpret_cast<uint4*>(&kvs[t * Dn + rlane * 8]) = pk;
      }
    }
  }

  // prefetch raw halves into registers (no LDS dependency -> before barrier)
  int l8 = tid & 7, r8 = tid >> 3;     // 8 lanes/row, rows r8 and 32+r8
  int ta = r8, tb = 32 + r8;
  bool hasb = (tb < CR);
  uint4 ea, ra, eb2, rb2;
  {
    int iaa = hrow[ta], iba = rrow[ta];
    ea = *reinterpret_cast<const uint4*>(Af + (size_t)iaa * AFS + 128 + l8 * 8);
    ra = *reinterpret_cast<const uint4*>(Bf + (size_t)iba * AFS + 128 + l8 * 8);
    if (hasb) {
      int iab = hrow[tb], ibb = rrow[tb];
      eb2 = *reinterpret_cast<const uint4*>(Af + (size_t)iab * AFS + 128 + l8 * 8);
      rb2 = *reinterpret_cast<const uint4*>(Bf + (size_t)ibb * AFS + 128 + l8 * 8);
    }
  }
  __syncthreads();  // kvs + tgtE/uvf/qv ready

  // raw dots from prefetched registers
#pragma unroll
  for (int pass = 0; pass < 2; pass++) {
    if (pass == 1 && !hasb) break;
    uint4 e = (pass == 0) ? ea : eb2;
    uint4 r = (pass == 0) ? ra : rb2;
    int t = (pass == 0) ? ta : tb;
    float2 e0 = pb2f2(e.x), e1 = pb2f2(e.y), e2 = pb2f2(e.z), e3 = pb2f2(e.w);
    float2 r0 = pb2f2(r.x), r1 = pb2f2(r.y), r2 = pb2f2(r.z), r3 = pb2f2(r.w);
    const float* u0 = &uvf[l8 * 8];       const float* t0 = &tgtE[l8 * 8];
    const float* u1 = &uvf[64 + l8 * 8];  const float* t1 = &tgtE[64 + l8 * 8];
    float s1a = e0.x * u0[0] + e0.y * u0[1] + e1.x * u0[2] + e1.y * u0[3]
              + e2.x * u0[4] + e2.y * u0[5] + e3.x * u0[6] + e3.y * u0[7]
              + r0.x * u1[0] + r0.y * u1[1] + r1.x * u1[2] + r1.y * u1[3]
              + r2.x * u1[4] + r2.y * u1[5] + r3.x * u1[6] + r3.y * u1[7];
    float s2a = e0.x * t0[0] + e0.y * t0[1] + e1.x * t0[2] + e1.y * t0[3]
              + e2.x * t0[4] + e2.y * t0[5] + e3.x * t0[6] + e3.y * t0[7]
              + r0.x * t1[0] + r0.y * t1[1] + r1.x * t1[2] + r1.y * t1[3]
              + r2.x * t1[4] + r2.y * t1[5] + r3.x * t1[6] + r3.y * t1[7];
    s1a += __shfl_xor(s1a, 1, 64); s2a += __shfl_xor(s2a, 1, 64);
    s1a += __shfl_xor(s1a, 2, 64); s2a += __shfl_xor(s2a, 2, 64);
    s1a += __shfl_xor(s1a, 4, 64); s2a += __shfl_xor(s2a, 4, 64);
    if (l8 == 0) s12[(size_t)i * Hn + CR * h + t] = make_float2(s1a, s2a);
  }

  // scores: buffer halfword index a'*200 + c (zero address math)
  if (tid < Hn) {
    float acc = 0.f;
    const USH* kp = &kvs[tid];
#pragma unroll
    for (int a = 0; a < 32; a++) acc += qv[a] * bf2f(kp[a * 200]);
    psc[((size_t)i * 4 + h) * Hn + tid] = acc;
  }
}

// ---------------------------------------------------------------------------
// Epilogue: one block per batch row. Fully coalesced — no gathers.
// ---------------------------------------------------------------------------
__global__ __launch_bounds__(256, 8) void ep_kernel(
    const int* __restrict__ history, const int* __restrict__ target,
    const float* __restrict__ hv, const float* __restrict__ dist_mat,
    const float* __restrict__ g, const float* __restrict__ psc,
    const float2* __restrict__ s12, float* __restrict__ out) {
  __shared__ float red[8];
  int i = blockIdx.x, tid = threadIdx.x, lane = tid & 63, wave = tid >> 6;
  int tgt_i = target[i];

  float ea = 0.f; float2 sv = make_float2(0.f, 0.f);
  if (tid < Hn) {
    const float* pp = psc + (size_t)i * 4 * Hn + tid;
    float s = (pp[0] + pp[Hn]) + (pp[2 * Hn] + pp[3 * Hn]);
    sv = s12[(size_t)i * Hn + tid];
    ea = (history[(size_t)i * Hn + tid] != tgt_i) ? __expf(s) : 0.f;
  }
  float wsum = ea;
  for (int off = 32; off > 0; off >>= 1) wsum += __shfl_down(wsum, off, 64);
  if (lane == 0) red[wave] = wsum;
  __syncthreads();
  float esum = red[0] + red[1] + red[2] + red[3];
  float inv = esum > 0.f ? 1.f / sqrtf(esum) : 0.f;  // exp_sum ** 0.5 (BETA)

  float part = 0.f;
  if (tid < Hn) {
    float gc = g[tid]; gc = gc > 0.f ? gc : 0.f;  // relu
    float dm = dist_mat[(size_t)i * Hn + tid];
    float geo = __expf(-dm / (gc + 1.f));
    part = (ea * inv + geo) * sv.x + hv[tid] * sv.y;
  }
  __syncthreads();  // protect red[] reuse
  for (int off = 32; off > 0; off >>= 1) part += __shfl_down(part, off, 64);
  if (lane == 0) red[wave] = part;
  __syncthreads();
  if (tid == 0) {
    float pred = red[0] + red[1] + red[2] + red[3];
    out[i] = 1.f / (1.f + __expf(-pred));
  }
}

extern "C" void kernel_launch(void* const* d_in, const int* in_sizes, int n_in,
                              void* d_out, int out_size, void* d_ws, size_t ws_size,
                              hipStream_t stream) {
  const int*   history = (const int*)d_in[0];
  const int*   target  = (const int*)d_in[1];
  const int*   hregion = (const int*)d_in[2];
  const int*   tregion = (const int*)d_in[3];
  const float* hv      = (const float*)d_in[4];
  const float* dist    = (const float*)d_in[5];
  const int*   uid     = (const int*)d_in[6];
  const float* Et      = (const float*)d_in[7];
  const float* Er      = (const float*)d_in[8];
  const float* Edist   = (const float*)d_in[9];
  const float* Wq      = (const float*)d_in[10];
  const float* Wk      = (const float*)d_in[11];
  const float* Wv      = (const float*)d_in[12];

  char* w = (char*)d_ws;
  float* g   = (float*)w;                            // 1KB slot
  USH*   Af  = (USH*)(w + 1024);                     // 50000*192 bf16 = 19.2MB
  USH*   Bf  = Af + (size_t)NITEM * AFS;             // 1000*192 bf16 = 384KB
  float* qvt = (float*)(Bf + (size_t)NREG * AFS);    // 1024*128 f32 = 512KB
  float* uvt = qvt + (size_t)Bn * Dn;                // 512KB
  float* psc = uvt + (size_t)Bn * Dn;                // 1024*4*200 f32 = 3.2MB
  float2* s12 = (float2*)(psc + (size_t)Bn * 4 * Hn);// 1024*200 float2 = 1.6MB
  float* out = (float*)d_out;

  hipMemsetAsync(g, 0, Hn * sizeof(float), stream);
  ab_kernel<<<AB_TOT + QU_BLOCKS + G_BLOCKS, 256, 0, stream>>>(
      Et, Er, Wk, Wq, Wv, target, tregion, hregion, Edist, uid,
      Af, Bf, qvt, uvt, g);
  sc_kernel<<<Bn * 4, 256, 0, stream>>>(history, target, hregion, tregion,
                                        Et, Er, qvt, uvt, Af, Bf, psc, s12);
  ep_kernel<<<Bn, 256, 0, stream>>>(history, target, hv, dist, g, psc, s12, out);
}